// Round 8
// baseline (345.890 us; speedup 1.0000x reference)
//
#include <hip/hip_runtime.h>
#include <hip/hip_fp16.h>

#define DIM 128
#define KCODES 1024
#define BROWS 128         // rows per block = 2 waves x 64 rows
#define NCH (KCODES / 16) // 64 chunks of 16 codes
#define TAU_ACC 3.0e-3f   // acc units; single-pass fp16 err ~3e-4 rms -> ~9 sigma (r7: passed, absmax 0)

typedef _Float16 f16x8 __attribute__((ext_vector_type(8)));
typedef float f32x4 __attribute__((ext_vector_type(4)));

// ---------- prep A: ||e_k||^2 (identical arithmetic to passing kernel) ----------
__global__ void enorm_kernel(const float* __restrict__ embed, float* __restrict__ enorm) {
    int k = blockIdx.x * blockDim.x + threadIdx.x;
    if (k < KCODES) {
        const float4* row = (const float4*)(embed + (size_t)k * DIM);
        float s = 0.f;
#pragma unroll
        for (int d = 0; d < DIM / 4; ++d) {
            float4 v = row[d];
            s = fmaf(v.x, v.x, s); s = fmaf(v.y, v.y, s);
            s = fmaf(v.z, v.z, s); s = fmaf(v.w, v.w, s);
        }
        enorm[k] = s;
    }
}

// ---------- prep B: E -> fp16, MFMA-fragment-ordered coalesced layout ----------
// t = c*256 + ks*64 + q*16 + n  (dst seg == t):
//   Ehp[t*8 + j] = (f16) embed[c*16 + n][ks*32 + q*8 + j]
__global__ void pack_kernel(const float* __restrict__ embed, _Float16* __restrict__ Ehp) {
    int t = blockIdx.x * blockDim.x + threadIdx.x;   // 0 .. KCODES*16-1
    int n  = t & 15;
    int q  = (t >> 4) & 3;
    int ks = (t >> 6) & 3;
    int c  = t >> 8;
    const float* src = embed + (size_t)(c * 16 + n) * DIM + ks * 32 + q * 8;
    float4 a0 = *(const float4*)src;
    float4 a1 = *(const float4*)(src + 4);
    float f[8] = {a0.x, a0.y, a0.z, a0.w, a1.x, a1.y, a1.z, a1.w};
    f16x8 h8;
#pragma unroll
    for (int j = 0; j < 8; ++j) h8[j] = (_Float16)f[j];
    *(f16x8*)&Ehp[(size_t)t * 8] = h8;
}

// ---------- main: 64 rows/wave, single-pass fp16, 4 independent MFMA chains/chunk ----------
// Round-8 deltas vs round-7: 4 rowsets per wave (16 MFMA per 4KB B-chunk -> 2x
// compute per B-byte, 4 independent chains), 128-thread blocks (grid 750, the
// best-measured shape), launch_bounds(128,2) = 256-VGPR cap so the dist-2
// named-register B pipeline can stay live. Math/refine identical to r7 (passed).
__global__ __launch_bounds__(128, 2)
void argmax_mfma_kernel(const float* __restrict__ x, const float* __restrict__ embed,
                        const _Float16* __restrict__ Ehp, const float* __restrict__ enorm,
                        float* __restrict__ outq, float* __restrict__ outi) {
    __shared__ float enorm_l[KCODES];   // -0.5*||e||^2
    __shared__ int idx_l[BROWS];
    __shared__ int flist[BROWS];
    __shared__ int fcnt;

    const int tid  = threadIdx.x;
    const int w    = tid >> 6;       // wave 0..1
    const int lane = tid & 63;
    const int n    = lane & 15;      // code col / A row class
    const int q    = lane >> 4;      // k-segment (A/B) / C row group
    const size_t row0 = (size_t)blockIdx.x * BROWS;

    if (tid == 0) fcnt = 0;
    {   // enorm -> LDS as -0.5*||e||^2 (folded into MFMA C-init); 2 float4 per thread
#pragma unroll
        for (int i = 0; i < 2; ++i) {
            float4 e4 = ((const float4*)enorm)[tid + i * 128];
            float4 v; v.x = -0.5f * e4.x; v.y = -0.5f * e4.y; v.z = -0.5f * e4.z; v.w = -0.5f * e4.w;
            ((float4*)enorm_l)[tid + i * 128] = v;
        }
    }

    // B buffers: named individual registers (r4-proven no-spill rotation).
    const _Float16* EhpL = Ehp + (size_t)lane * 8;
    f16x8 bA0, bA1, bA2, bA3, bB0, bB1, bB2, bB3;
#define LOADB(P, B0, B1, B2, B3) do {                  \
    const _Float16* p_ = (P);                          \
    B0 = *(const f16x8*)(p_);                          \
    B1 = *(const f16x8*)(p_ + 512);                    \
    B2 = *(const f16x8*)(p_ + 1024);                   \
    B3 = *(const f16x8*)(p_ + 1536); } while (0)

    // issue chunk 0/1 loads early (latency hides under A conversion below)
    LOADB(EhpL, bA0, bA1, bA2, bA3);
    LOADB(EhpL + 2048, bB0, bB1, bB2, bB3);

    // A fragments: this wave's 64 rows (4 rowsets of 16), fp16 single-pass.
    // layout: A[m = lane&15][k = ks*32 + q*8 + j]  (geometry verified, passing)
    f16x8 xh[4][4];
#pragma unroll
    for (int s = 0; s < 4; ++s)
#pragma unroll
        for (int ks = 0; ks < 4; ++ks) {
            const float* xp = x + (row0 + (size_t)(w * 64 + s * 16 + n)) * DIM + ks * 32 + q * 8;
            float4 a0 = *(const float4*)xp;
            float4 a1 = *(const float4*)(xp + 4);
            float f[8] = {a0.x, a0.y, a0.z, a0.w, a1.x, a1.y, a1.z, a1.w};
            f16x8 h;
#pragma unroll
            for (int j = 0; j < 8; ++j) h[j] = (_Float16)f[j];
            xh[s][ks] = h;
        }

    __syncthreads();   // enorm_l ready

    float best[4][4], sec[4][4]; int bidx[4][4];
#pragma unroll
    for (int s = 0; s < 4; ++s)
#pragma unroll
        for (int rg = 0; rg < 4; ++rg) { best[s][rg] = -3.4e38f; sec[s][rg] = -3.4e38f; bidx[s][rg] = 0; }

// one 16-code chunk: 4 independent MFMA chains of depth 4 (one per rowset),
// round-robin issue; C-init = -0.5*||e||^2 -> acc = x.e - ||e||^2/2 directly.
#define PROC(CI, B0, B1, B2, B3, EV) do {                                             \
    const int code_ = (CI) * 16 + n;                                                  \
    f32x4 a0 = {EV, EV, EV, EV};                                                      \
    f32x4 a1 = {EV, EV, EV, EV};                                                      \
    f32x4 a2 = {EV, EV, EV, EV};                                                      \
    f32x4 a3 = {EV, EV, EV, EV};                                                      \
    a0 = __builtin_amdgcn_mfma_f32_16x16x32_f16(xh[0][0], B0, a0, 0, 0, 0);           \
    a1 = __builtin_amdgcn_mfma_f32_16x16x32_f16(xh[1][0], B0, a1, 0, 0, 0);           \
    a2 = __builtin_amdgcn_mfma_f32_16x16x32_f16(xh[2][0], B0, a2, 0, 0, 0);           \
    a3 = __builtin_amdgcn_mfma_f32_16x16x32_f16(xh[3][0], B0, a3, 0, 0, 0);           \
    a0 = __builtin_amdgcn_mfma_f32_16x16x32_f16(xh[0][1], B1, a0, 0, 0, 0);           \
    a1 = __builtin_amdgcn_mfma_f32_16x16x32_f16(xh[1][1], B1, a1, 0, 0, 0);           \
    a2 = __builtin_amdgcn_mfma_f32_16x16x32_f16(xh[2][1], B1, a2, 0, 0, 0);           \
    a3 = __builtin_amdgcn_mfma_f32_16x16x32_f16(xh[3][1], B1, a3, 0, 0, 0);           \
    a0 = __builtin_amdgcn_mfma_f32_16x16x32_f16(xh[0][2], B2, a0, 0, 0, 0);           \
    a1 = __builtin_amdgcn_mfma_f32_16x16x32_f16(xh[1][2], B2, a1, 0, 0, 0);           \
    a2 = __builtin_amdgcn_mfma_f32_16x16x32_f16(xh[2][2], B2, a2, 0, 0, 0);           \
    a3 = __builtin_amdgcn_mfma_f32_16x16x32_f16(xh[3][2], B2, a3, 0, 0, 0);           \
    a0 = __builtin_amdgcn_mfma_f32_16x16x32_f16(xh[0][3], B3, a0, 0, 0, 0);           \
    a1 = __builtin_amdgcn_mfma_f32_16x16x32_f16(xh[1][3], B3, a1, 0, 0, 0);           \
    a2 = __builtin_amdgcn_mfma_f32_16x16x32_f16(xh[2][3], B3, a2, 0, 0, 0);           \
    a3 = __builtin_amdgcn_mfma_f32_16x16x32_f16(xh[3][3], B3, a3, 0, 0, 0);           \
    _Pragma("unroll")                                                                 \
    for (int rg = 0; rg < 4; ++rg) {                                                  \
        float sc0 = a0[rg];                                                           \
        sec[0][rg]  = __builtin_amdgcn_fmed3f(best[0][rg], sec[0][rg], sc0);          \
        bidx[0][rg] = (sc0 > best[0][rg]) ? code_ : bidx[0][rg];                      \
        best[0][rg] = fmaxf(best[0][rg], sc0);                                        \
        float sc1 = a1[rg];                                                           \
        sec[1][rg]  = __builtin_amdgcn_fmed3f(best[1][rg], sec[1][rg], sc1);          \
        bidx[1][rg] = (sc1 > best[1][rg]) ? code_ : bidx[1][rg];                      \
        best[1][rg] = fmaxf(best[1][rg], sc1);                                        \
        float sc2 = a2[rg];                                                           \
        sec[2][rg]  = __builtin_amdgcn_fmed3f(best[2][rg], sec[2][rg], sc2);          \
        bidx[2][rg] = (sc2 > best[2][rg]) ? code_ : bidx[2][rg];                      \
        best[2][rg] = fmaxf(best[2][rg], sc2);                                        \
        float sc3 = a3[rg];                                                           \
        sec[3][rg]  = __builtin_amdgcn_fmed3f(best[3][rg], sec[3][rg], sc3);          \
        bidx[3][rg] = (sc3 > best[3][rg]) ? code_ : bidx[3][rg];                      \
        best[3][rg] = fmaxf(best[3][rg], sc3);                                        \
    }                                                                                 \
} while (0)

    float eA = enorm_l[0 * 16 + n];
    float eB = enorm_l[1 * 16 + n];
#pragma unroll 1
    for (int cc = 0; cc < NCH; cc += 2) {
        float eA2 = enorm_l[((cc + 2) & (NCH - 1)) * 16 + n];
        float eB2 = enorm_l[((cc + 3) & (NCH - 1)) * 16 + n];
        const _Float16* p2 = EhpL + (size_t)((cc + 2) & (NCH - 1)) * 2048;
        const _Float16* p3 = EhpL + (size_t)((cc + 3) & (NCH - 1)) * 2048;
        PROC(cc, bA0, bA1, bA2, bA3, eA);
        LOADB(p2, bA0, bA1, bA2, bA3);          // reload A-buffer for chunk cc+2
        PROC(cc + 1, bB0, bB1, bB2, bB3, eB);
        LOADB(p3, bB0, bB1, bB2, bB3);          // reload B-buffer for chunk cc+3
        eA = eA2; eB = eB2;
    }
#undef PROC
#undef LOADB

    // reduce top-2 across the 16 col classes (lane bits 0..3)
#pragma unroll
    for (int mask = 1; mask < 16; mask <<= 1) {
#pragma unroll
        for (int s = 0; s < 4; ++s)
#pragma unroll
            for (int rg = 0; rg < 4; ++rg) {
                float ob = __shfl_xor(best[s][rg], mask);
                float os = __shfl_xor(sec[s][rg], mask);
                int   oi = __shfl_xor(bidx[s][rg], mask);
                if (ob > best[s][rg] || (ob == best[s][rg] && oi < bidx[s][rg])) {
                    sec[s][rg] = fmaxf(best[s][rg], os);
                    best[s][rg] = ob; bidx[s][rg] = oi;
                } else {
                    sec[s][rg] = fmaxf(sec[s][rg], ob);
                }
            }
    }
    if (n == 0) {
#pragma unroll
        for (int s = 0; s < 4; ++s)
#pragma unroll
            for (int rg = 0; rg < 4; ++rg) {
                int r = w * 64 + s * 16 + q * 4 + rg;
                idx_l[r] = bidx[s][rg];
                if (best[s][rg] - sec[s][rg] < TAU_ACC) {
                    int p = atomicAdd(&fcnt, 1);
                    flist[p] = r;
                }
            }
    }
    __syncthreads();

    // exact fp32 refine for near-tie rows, wave-per-row (lane handles 16 codes;
    // per-code arithmetic identical to passing kernel)
    int nf = fcnt;
    for (int f = w; f < nf; f += 2) {
        int r = flist[f];
        const float4* xg4 = (const float4*)(x + (row0 + r) * DIM);
        float b = -3.4e38f; int bi = 0;
        for (int c = lane * 16; c < lane * 16 + 16; ++c) {
            const float4* eg4 = (const float4*)(embed + (size_t)c * DIM);
            float s = 0.f;
#pragma unroll 8
            for (int d = 0; d < DIM / 4; ++d) {
                float4 xv = xg4[d], ev = eg4[d];
                s = fmaf(xv.x, ev.x, s); s = fmaf(xv.y, ev.y, s);
                s = fmaf(xv.z, ev.z, s); s = fmaf(xv.w, ev.w, s);
            }
            float sc = fmaf(2.f, s, -enorm[c]);
            if (sc > b) { b = sc; bi = c; }
        }
#pragma unroll
        for (int mask = 1; mask < 64; mask <<= 1) {
            float ob = __shfl_xor(b, mask);
            int   oi = __shfl_xor(bi, mask);
            if (ob > b || (ob == b && oi < bi)) { b = ob; bi = oi; }
        }
        if (lane == 0) idx_l[r] = bi;
    }
    __syncthreads();

    // fused gather (embed L2-resident) + float index write
    const float4* e4 = (const float4*)embed;
    float4* oq4 = (float4*)outq + row0 * (DIM / 4);
#pragma unroll
    for (int i = 0; i < 32; ++i) {
        int g = tid + i * 128;
        int r = g >> 5, d4 = g & 31;
        int id = idx_l[r];
        oq4[g] = e4[(size_t)id * (DIM / 4) + d4];
    }
    if (tid < BROWS) outi[row0 + tid] = (float)idx_l[tid];
}

extern "C" void kernel_launch(void* const* d_in, const int* in_sizes, int n_in,
                              void* d_out, int out_size, void* d_ws, size_t ws_size,
                              hipStream_t stream) {
    const float* x     = (const float*)d_in[0];
    const float* embed = (const float*)d_in[1];
    const int x_elems  = in_sizes[0];          // 12,288,000
    const int n_rows   = x_elems / DIM;        // 96,000

    float*    enorm = (float*)d_ws;                              // 4 KB
    _Float16* Ehp   = (_Float16*)((char*)d_ws + 4096);           // 256 KB

    float* outq = (float*)d_out;
    float* outi = (float*)d_out + (size_t)x_elems;

    enorm_kernel<<<KCODES / 256, 256, 0, stream>>>(embed, enorm);
    pack_kernel<<<KCODES * 16 / 256, 256, 0, stream>>>(embed, Ehp);
    argmax_mfma_kernel<<<n_rows / BROWS, 128, 0, stream>>>(x, embed, Ehp, enorm, outq, outi);
}

// Round 9
// 301.038 us; speedup vs baseline: 1.1490x; 1.1490x over previous
//
#include <hip/hip_runtime.h>
#include <hip/hip_fp16.h>

#define DIM 128
#define KCODES 1024
#define BROWS 128                 // rows per block = 4 waves x 32 rows
#define CCH 32                    // codes per staged chunk (8 KB)
#define NCHK (KCODES / CCH)       // 32 chunks
#define NBUF 4                    // LDS ring buffers (stage t+3 while reading t)
#define TAU_ACC 3.0e-3f           // acc units; single-pass fp16 err ~3e-4 rms (r7: passed, absmax 0)

typedef _Float16 f16x8 __attribute__((ext_vector_type(8)));
typedef float f32x4 __attribute__((ext_vector_type(4)));

__device__ __forceinline__ void gl_lds16(const void* g, void* l) {
    __builtin_amdgcn_global_load_lds(
        (const __attribute__((address_space(1))) void*)g,
        (__attribute__((address_space(3))) void*)l, 16, 0, 0);
}

// ---------- prep A: ||e_k||^2 (identical arithmetic to passing kernel) ----------
__global__ void enorm_kernel(const float* __restrict__ embed, float* __restrict__ enorm) {
    int k = blockIdx.x * blockDim.x + threadIdx.x;
    if (k < KCODES) {
        const float4* row = (const float4*)(embed + (size_t)k * DIM);
        float s = 0.f;
#pragma unroll
        for (int d = 0; d < DIM / 4; ++d) {
            float4 v = row[d];
            s = fmaf(v.x, v.x, s); s = fmaf(v.y, v.y, s);
            s = fmaf(v.z, v.z, s); s = fmaf(v.w, v.w, s);
        }
        enorm[k] = s;
    }
}

// ---------- prep B: E -> fp16, MFMA-fragment-ordered coalesced layout ----------
// t = c*256 + ks*64 + q*16 + n  (dst seg == t):
//   Ehp[t*8 + j] = (f16) embed[c*16 + n][ks*32 + q*8 + j]
// Lane-linear -> global_load_lds staging produces a verbatim LDS image.
__global__ void pack_kernel(const float* __restrict__ embed, _Float16* __restrict__ Ehp) {
    int t = blockIdx.x * blockDim.x + threadIdx.x;   // 0 .. KCODES*16-1
    int n  = t & 15;
    int q  = (t >> 4) & 3;
    int ks = (t >> 6) & 3;
    int c  = t >> 8;
    const float* src = embed + (size_t)(c * 16 + n) * DIM + ks * 32 + q * 8;
    float4 a0 = *(const float4*)src;
    float4 a1 = *(const float4*)(src + 4);
    float f[8] = {a0.x, a0.y, a0.z, a0.w, a1.x, a1.y, a1.z, a1.w};
    f16x8 h8;
#pragma unroll
    for (int j = 0; j < 8; ++j) h8[j] = (_Float16)f[j];
    *(f16x8*)&Ehp[(size_t)t * 8] = h8;
}

// ---------- main: T3/T4 counted-vmcnt pipeline, single-pass fp16 MFMA argmax ----------
// Round-9 deltas: 4-deep LDS ring staged via global_load_lds with inline-asm
// s_waitcnt vmcnt(4) (never 0) + raw s_barrier per chunk -> prefetch distance is
// pinned by asm, immune to the register allocator (r7/r8 failure mode). Stage of
// chunk t+3 is issued BEFORE compute of chunk t; each stage flies >=2 chunk
// periods. Single-pass fp16 (r7-verified) + setprio around MFMA (T5).
__global__ __launch_bounds__(256, 4)
void argmax_mfma_kernel(const float* __restrict__ x, const float* __restrict__ embed,
                        const _Float16* __restrict__ Ehp, const float* __restrict__ enorm,
                        float* __restrict__ outq, float* __restrict__ outi) {
    __shared__ __align__(16) _Float16 ebuf[NBUF][CCH * DIM];  // 4 x 8 KB
    __shared__ float enorm_l[KCODES];   // -0.5*||e||^2
    __shared__ int idx_l[BROWS];
    __shared__ int flist[BROWS];
    __shared__ float rbest[4];
    __shared__ int   rbidx[4];
    __shared__ int fcnt;

    const int tid  = threadIdx.x;
    const int w    = tid >> 6;       // wave 0..3
    const int lane = tid & 63;
    const int n    = lane & 15;      // code col / A row class
    const int q    = lane >> 4;      // k-segment (A/B) / C row group
    const size_t row0 = (size_t)blockIdx.x * BROWS;

    if (tid == 0) fcnt = 0;
    {   // enorm -> LDS as -0.5*||e||^2 (folded into MFMA C-init)
        float4 e4 = ((const float4*)enorm)[tid];
        float4 v; v.x = -0.5f * e4.x; v.y = -0.5f * e4.y; v.z = -0.5f * e4.z; v.w = -0.5f * e4.w;
        ((float4*)enorm_l)[tid] = v;
    }

    // prologue staging: chunks 0,1,2 (wave w stages 2 KB of each 8 KB chunk)
#pragma unroll
    for (int pt = 0; pt < 3; ++pt) {
        const _Float16* gsrc = Ehp + (size_t)pt * (CCH * DIM) + (size_t)(w * 1024) + (size_t)lane * 8;
        _Float16* ldst = &ebuf[pt][w * 1024];
        gl_lds16(gsrc, ldst);
        gl_lds16(gsrc + 512, ldst + 512);
    }

    // A fragments: this wave's 32 rows (2 rowsets of 16), fp16 single-pass.
    // layout: A[m = lane&15][k = ks*32 + q*8 + j]  (geometry verified, passing)
    f16x8 xh[2][4];
#pragma unroll
    for (int s = 0; s < 2; ++s)
#pragma unroll
        for (int ks = 0; ks < 4; ++ks) {
            const float* xp = x + (row0 + (size_t)(w * 32 + s * 16 + n)) * DIM + ks * 32 + q * 8;
            float4 a0 = *(const float4*)xp;
            float4 a1 = *(const float4*)(xp + 4);
            float f[8] = {a0.x, a0.y, a0.z, a0.w, a1.x, a1.y, a1.z, a1.w};
            f16x8 h;
#pragma unroll
            for (int j = 0; j < 8; ++j) h[j] = (_Float16)f[j];
            xh[s][ks] = h;
        }

    __syncthreads();   // enorm_l visible; prologue stages drained (full sync OK here)

    float best[2][4], sec[2][4]; int bidx[2][4];
#pragma unroll
    for (int s = 0; s < 2; ++s)
#pragma unroll
        for (int rg = 0; rg < 4; ++rg) { best[s][rg] = -3.4e38f; sec[s][rg] = -3.4e38f; bidx[s][rg] = 0; }

// one 16-code group from LDS: per-ks {1 ds_read_b128 -> 2 MFMA}, then top-2 update.
// C-init = -0.5*||e||^2 -> acc = x.e - ||e||^2/2 directly. (r7-verified math)
#define PROC(CI, EBC, EV) do {                                                        \
    const int code_ = (CI) * 16 + n;                                                  \
    const _Float16* ebc_ = (EBC) + (size_t)lane * 8;                                  \
    f32x4 a0 = {EV, EV, EV, EV};                                                      \
    f32x4 a1 = {EV, EV, EV, EV};                                                      \
    _Pragma("unroll")                                                                 \
    for (int ks_ = 0; ks_ < 4; ++ks_) {                                               \
        f16x8 B = *(const f16x8*)(ebc_ + ks_ * 512);                                  \
        a0 = __builtin_amdgcn_mfma_f32_16x16x32_f16(xh[0][ks_], B, a0, 0, 0, 0);      \
        a1 = __builtin_amdgcn_mfma_f32_16x16x32_f16(xh[1][ks_], B, a1, 0, 0, 0);      \
    }                                                                                 \
    _Pragma("unroll")                                                                 \
    for (int rg = 0; rg < 4; ++rg) {                                                  \
        float sc0 = a0[rg];                                                           \
        sec[0][rg]  = __builtin_amdgcn_fmed3f(best[0][rg], sec[0][rg], sc0);          \
        bidx[0][rg] = (sc0 > best[0][rg]) ? code_ : bidx[0][rg];                      \
        best[0][rg] = fmaxf(best[0][rg], sc0);                                        \
        float sc1 = a1[rg];                                                           \
        sec[1][rg]  = __builtin_amdgcn_fmed3f(best[1][rg], sec[1][rg], sc1);          \
        bidx[1][rg] = (sc1 > best[1][rg]) ? code_ : bidx[1][rg];                      \
        best[1][rg] = fmaxf(best[1][rg], sc1);                                        \
    }                                                                                 \
} while (0)

    // main loop: stage(t+3) -> compute(t) -> vmcnt(4) -> barrier.
    // vmcnt(4): of the 6 outstanding stage-loads (t+1,t+2,t+3), wait until only
    // 4 remain -> chunk t+1 fully landed (for every wave; barrier makes it global).
#pragma unroll 1
    for (int t = 0; t < NCHK; ++t) {
        {   // stage chunk (t+3)&31 into buf[(t+3)&3] (wrap: harmless re-stage at tail)
            const int tc = (t + 3) & (NCHK - 1);
            const _Float16* gsrc = Ehp + (size_t)tc * (CCH * DIM) + (size_t)(w * 1024) + (size_t)lane * 8;
            _Float16* ldst = &ebuf[(t + 3) & (NBUF - 1)][w * 1024];
            gl_lds16(gsrc, ldst);
            gl_lds16(gsrc + 512, ldst + 512);
        }
        const _Float16* eb = &ebuf[t & (NBUF - 1)][0];
        float e0 = enorm_l[t * CCH + n];
        float e1 = enorm_l[t * CCH + 16 + n];
        __builtin_amdgcn_s_setprio(1);
        PROC(t * 2,     eb,        e0);
        PROC(t * 2 + 1, eb + 2048, e1);
        __builtin_amdgcn_s_setprio(0);
        asm volatile("s_waitcnt vmcnt(4)" ::: "memory");
        __builtin_amdgcn_s_barrier();
    }
#undef PROC

    // reduce top-2 across the 16 col classes (lane bits 0..3)
#pragma unroll
    for (int mask = 1; mask < 16; mask <<= 1) {
#pragma unroll
        for (int s = 0; s < 2; ++s)
#pragma unroll
            for (int rg = 0; rg < 4; ++rg) {
                float ob = __shfl_xor(best[s][rg], mask);
                float os = __shfl_xor(sec[s][rg], mask);
                int   oi = __shfl_xor(bidx[s][rg], mask);
                if (ob > best[s][rg] || (ob == best[s][rg] && oi < bidx[s][rg])) {
                    sec[s][rg] = fmaxf(best[s][rg], os);
                    best[s][rg] = ob; bidx[s][rg] = oi;
                } else {
                    sec[s][rg] = fmaxf(sec[s][rg], ob);
                }
            }
    }
    if (n == 0) {
#pragma unroll
        for (int s = 0; s < 2; ++s)
#pragma unroll
            for (int rg = 0; rg < 4; ++rg) {
                int r = w * 32 + s * 16 + q * 4 + rg;
                idx_l[r] = bidx[s][rg];
                if (best[s][rg] - sec[s][rg] < TAU_ACC) {
                    int p = atomicAdd(&fcnt, 1);
                    flist[p] = r;
                }
            }
    }
    __syncthreads();

    // exact fp32 refine for near-tie rows, COOPERATIVE: all 256 threads per row
    // (lane handles 4 codes; per-code arithmetic identical to passing kernel)
    int nf = fcnt;
    for (int f = 0; f < nf; ++f) {
        int r = flist[f];
        const float4* xg4 = (const float4*)(x + (row0 + r) * DIM);
        float b = -3.4e38f; int bi = 0;
        int cbase = w * 256 + lane * 4;
        for (int c = cbase; c < cbase + 4; ++c) {
            const float4* eg4 = (const float4*)(embed + (size_t)c * DIM);
            float s = 0.f;
#pragma unroll 8
            for (int d = 0; d < DIM / 4; ++d) {
                float4 xv = xg4[d], ev = eg4[d];
                s = fmaf(xv.x, ev.x, s); s = fmaf(xv.y, ev.y, s);
                s = fmaf(xv.z, ev.z, s); s = fmaf(xv.w, ev.w, s);
            }
            float sc = fmaf(2.f, s, -enorm[c]);
            if (sc > b) { b = sc; bi = c; }
        }
#pragma unroll
        for (int mask = 1; mask < 64; mask <<= 1) {
            float ob = __shfl_xor(b, mask);
            int   oi = __shfl_xor(bi, mask);
            if (ob > b || (ob == b && oi < bi)) { b = ob; bi = oi; }
        }
        if (lane == 0) { rbest[w] = b; rbidx[w] = bi; }
        __syncthreads();
        if (tid == 0) {
            float B = rbest[0]; int BI = rbidx[0];
#pragma unroll
            for (int i = 1; i < 4; ++i)
                if (rbest[i] > B || (rbest[i] == B && rbidx[i] < BI)) { B = rbest[i]; BI = rbidx[i]; }
            idx_l[r] = BI;
        }
        __syncthreads();
    }
    __syncthreads();

    // fused gather (embed L2-resident) + float index write
    const float4* e4 = (const float4*)embed;
    float4* oq4 = (float4*)outq + row0 * (DIM / 4);
#pragma unroll
    for (int i = 0; i < 16; ++i) {
        int g = tid + i * 256;
        int r = g >> 5, d4 = g & 31;
        int id = idx_l[r];
        oq4[g] = e4[(size_t)id * (DIM / 4) + d4];
    }
    if (tid < BROWS) outi[row0 + tid] = (float)idx_l[tid];
}

extern "C" void kernel_launch(void* const* d_in, const int* in_sizes, int n_in,
                              void* d_out, int out_size, void* d_ws, size_t ws_size,
                              hipStream_t stream) {
    const float* x     = (const float*)d_in[0];
    const float* embed = (const float*)d_in[1];
    const int x_elems  = in_sizes[0];          // 12,288,000
    const int n_rows   = x_elems / DIM;        // 96,000

    float*    enorm = (float*)d_ws;                              // 4 KB
    _Float16* Ehp   = (_Float16*)((char*)d_ws + 4096);           // 256 KB

    float* outq = (float*)d_out;
    float* outi = (float*)d_out + (size_t)x_elems;

    enorm_kernel<<<KCODES / 256, 256, 0, stream>>>(embed, enorm);
    pack_kernel<<<KCODES * 16 / 256, 256, 0, stream>>>(embed, Ehp);
    argmax_mfma_kernel<<<n_rows / BROWS, 256, 0, stream>>>(x, embed, Ehp, enorm, outq, outi);
}

// Round 10
// 198.187 us; speedup vs baseline: 1.7453x; 1.5190x over previous
//
#include <hip/hip_runtime.h>
#include <hip/hip_fp16.h>

#define DIM 128
#define KCODES 1024
#define BROWS 128         // rows per block = 4 waves x 32 rows
#define NCH (KCODES / 16) // 64 chunks of 16 codes
#define TAU_ACC 1.2e-3f   // acc units (= x.e - ||e||^2/2); fp16 2-pass err ~1.6e-4 rms

typedef _Float16 f16x8 __attribute__((ext_vector_type(8)));
typedef float f32x4 __attribute__((ext_vector_type(4)));

// ---------- prep A: ||e_k||^2 (identical arithmetic to passing kernel) + fcnt zero ----------
__global__ void enorm_kernel(const float* __restrict__ embed, float* __restrict__ enorm,
                             int* __restrict__ fcnt_g) {
    int k = blockIdx.x * blockDim.x + threadIdx.x;
    if (k == 0) *fcnt_g = 0;          // stream-ordered before main kernel
    if (k < KCODES) {
        const float4* row = (const float4*)(embed + (size_t)k * DIM);
        float s = 0.f;
#pragma unroll
        for (int d = 0; d < DIM / 4; ++d) {
            float4 v = row[d];
            s = fmaf(v.x, v.x, s); s = fmaf(v.y, v.y, s);
            s = fmaf(v.z, v.z, s); s = fmaf(v.w, v.w, s);
        }
        enorm[k] = s;
    }
}

// ---------- prep B: E -> fp16, MFMA-fragment-ordered coalesced layout ----------
// t = c*256 + ks*64 + q*16 + n  (dst seg == t):
//   Ehp[t*8 + j] = (f16) embed[c*16 + n][ks*32 + q*8 + j]
__global__ void pack_kernel(const float* __restrict__ embed, _Float16* __restrict__ Ehp) {
    int t = blockIdx.x * blockDim.x + threadIdx.x;   // 0 .. KCODES*16-1
    int n  = t & 15;
    int q  = (t >> 4) & 3;
    int ks = (t >> 6) & 3;
    int c  = t >> 8;
    const float* src = embed + (size_t)(c * 16 + n) * DIM + ks * 32 + q * 8;
    float4 a0 = *(const float4*)src;
    float4 a1 = *(const float4*)(src + 4);
    float f[8] = {a0.x, a0.y, a0.z, a0.w, a1.x, a1.y, a1.z, a1.w};
    f16x8 h8;
#pragma unroll
    for (int j = 0; j < 8; ++j) h8[j] = (_Float16)f[j];
    *(f16x8*)&Ehp[(size_t)t * 8] = h8;
}

// ---------- dispatch 1: r4 main loop verbatim, ends at top-2; writes outi + flag list ----------
// Round-10 delta: refine & gather moved to their own dispatches (phase ablation +
// kills the serial per-block tail). Main-loop math/selection identical to r4 (passed).
__global__ __launch_bounds__(256, 3)
void argmax_mfma_kernel(const float* __restrict__ x,
                        const _Float16* __restrict__ Ehp, const float* __restrict__ enorm,
                        float* __restrict__ outi, int* __restrict__ fcnt_g,
                        int* __restrict__ flags) {
    __shared__ float enorm_l[KCODES];   // -0.5*||e||^2

    const int tid  = threadIdx.x;
    const int w    = tid >> 6;       // wave 0..3
    const int lane = tid & 63;
    const int n    = lane & 15;      // code col / A row class
    const int q    = lane >> 4;      // k-segment (A/B) / C row group
    const size_t row0 = (size_t)blockIdx.x * BROWS;

    {   // enorm -> LDS as -0.5*||e||^2 (folded into MFMA C-init)
        float4 e4 = ((const float4*)enorm)[tid];
        float4 v; v.x = -0.5f * e4.x; v.y = -0.5f * e4.y; v.z = -0.5f * e4.z; v.w = -0.5f * e4.w;
        ((float4*)enorm_l)[tid] = v;
    }

    // B buffers: named individual registers (r4-proven no-spill rotation).
    const _Float16* EhpL = Ehp + (size_t)lane * 8;
    f16x8 bA0, bA1, bA2, bA3, bB0, bB1, bB2, bB3;
#define LOADB(P, B0, B1, B2, B3) do {                  \
    const _Float16* p_ = (P);                          \
    B0 = *(const f16x8*)(p_);                          \
    B1 = *(const f16x8*)(p_ + 512);                    \
    B2 = *(const f16x8*)(p_ + 1024);                   \
    B3 = *(const f16x8*)(p_ + 1536); } while (0)

    // issue chunk 0/1 loads early (latency hides under A conversion below)
    LOADB(EhpL, bA0, bA1, bA2, bA3);
    LOADB(EhpL + 2048, bB0, bB1, bB2, bB3);

    // A fragments: this wave's 32 rows (2 rowsets of 16), fp16 hi/lo split.
    // layout: A[m = lane&15][k = ks*32 + q*8 + j]  (geometry verified, passing)
    f16x8 xh[2][4], xl[2][4];
#pragma unroll
    for (int s = 0; s < 2; ++s)
#pragma unroll
        for (int ks = 0; ks < 4; ++ks) {
            const float* xp = x + (row0 + (size_t)(w * 32 + s * 16 + n)) * DIM + ks * 32 + q * 8;
            float4 a0 = *(const float4*)xp;
            float4 a1 = *(const float4*)(xp + 4);
            float f[8] = {a0.x, a0.y, a0.z, a0.w, a1.x, a1.y, a1.z, a1.w};
            f16x8 h, l;
#pragma unroll
            for (int j = 0; j < 8; ++j) {
                _Float16 hh = (_Float16)f[j];
                h[j] = hh;
                l[j] = (_Float16)(f[j] - (float)hh);
            }
            xh[s][ks] = h; xl[s][ks] = l;
        }

    __syncthreads();   // enorm_l ready

    float best[2][4], sec[2][4]; int bidx[2][4];
#pragma unroll
    for (int s = 0; s < 2; ++s)
#pragma unroll
        for (int rg = 0; rg < 4; ++rg) { best[s][rg] = -3.4e38f; sec[s][rg] = -3.4e38f; bidx[s][rg] = 0; }

// one 16-code chunk: 4 independent MFMA chains of depth 4, then top-2 update.
// hi-chain C-init = -0.5*||e||^2, lo-chain C-init = 0, merged with one add.
#define PROC(CI, B0, B1, B2, B3, EV) do {                                             \
    const int code_ = (CI) * 16 + n;                                                  \
    f32x4 h0 = {EV, EV, EV, EV}, l0 = {0.f, 0.f, 0.f, 0.f};                           \
    f32x4 h1 = {EV, EV, EV, EV}, l1 = {0.f, 0.f, 0.f, 0.f};                           \
    h0 = __builtin_amdgcn_mfma_f32_16x16x32_f16(xh[0][0], B0, h0, 0, 0, 0);           \
    h1 = __builtin_amdgcn_mfma_f32_16x16x32_f16(xh[1][0], B0, h1, 0, 0, 0);           \
    l0 = __builtin_amdgcn_mfma_f32_16x16x32_f16(xl[0][0], B0, l0, 0, 0, 0);           \
    l1 = __builtin_amdgcn_mfma_f32_16x16x32_f16(xl[1][0], B0, l1, 0, 0, 0);           \
    h0 = __builtin_amdgcn_mfma_f32_16x16x32_f16(xh[0][1], B1, h0, 0, 0, 0);           \
    h1 = __builtin_amdgcn_mfma_f32_16x16x32_f16(xh[1][1], B1, h1, 0, 0, 0);           \
    l0 = __builtin_amdgcn_mfma_f32_16x16x32_f16(xl[0][1], B1, l0, 0, 0, 0);           \
    l1 = __builtin_amdgcn_mfma_f32_16x16x32_f16(xl[1][1], B1, l1, 0, 0, 0);           \
    h0 = __builtin_amdgcn_mfma_f32_16x16x32_f16(xh[0][2], B2, h0, 0, 0, 0);           \
    h1 = __builtin_amdgcn_mfma_f32_16x16x32_f16(xh[1][2], B2, h1, 0, 0, 0);           \
    l0 = __builtin_amdgcn_mfma_f32_16x16x32_f16(xl[0][2], B2, l0, 0, 0, 0);           \
    l1 = __builtin_amdgcn_mfma_f32_16x16x32_f16(xl[1][2], B2, l1, 0, 0, 0);           \
    h0 = __builtin_amdgcn_mfma_f32_16x16x32_f16(xh[0][3], B3, h0, 0, 0, 0);           \
    h1 = __builtin_amdgcn_mfma_f32_16x16x32_f16(xh[1][3], B3, h1, 0, 0, 0);           \
    l0 = __builtin_amdgcn_mfma_f32_16x16x32_f16(xl[0][3], B3, l0, 0, 0, 0);           \
    l1 = __builtin_amdgcn_mfma_f32_16x16x32_f16(xl[1][3], B3, l1, 0, 0, 0);           \
    _Pragma("unroll")                                                                 \
    for (int rg = 0; rg < 4; ++rg) {                                                  \
        float sc0 = h0[rg] + l0[rg];                                                  \
        sec[0][rg]  = __builtin_amdgcn_fmed3f(best[0][rg], sec[0][rg], sc0);          \
        bidx[0][rg] = (sc0 > best[0][rg]) ? code_ : bidx[0][rg];                      \
        best[0][rg] = fmaxf(best[0][rg], sc0);                                        \
        float sc1 = h1[rg] + l1[rg];                                                  \
        sec[1][rg]  = __builtin_amdgcn_fmed3f(best[1][rg], sec[1][rg], sc1);          \
        bidx[1][rg] = (sc1 > best[1][rg]) ? code_ : bidx[1][rg];                      \
        best[1][rg] = fmaxf(best[1][rg], sc1);                                        \
    }                                                                                 \
} while (0)

    float eA = enorm_l[0 * 16 + n];
    float eB = enorm_l[1 * 16 + n];
#pragma unroll 1
    for (int cc = 0; cc < NCH; cc += 2) {
        float eA2 = enorm_l[((cc + 2) & (NCH - 1)) * 16 + n];
        float eB2 = enorm_l[((cc + 3) & (NCH - 1)) * 16 + n];
        const _Float16* p2 = EhpL + (size_t)((cc + 2) & (NCH - 1)) * 2048;
        const _Float16* p3 = EhpL + (size_t)((cc + 3) & (NCH - 1)) * 2048;
        PROC(cc, bA0, bA1, bA2, bA3, eA);
        LOADB(p2, bA0, bA1, bA2, bA3);          // reload A-buffer for chunk cc+2
        PROC(cc + 1, bB0, bB1, bB2, bB3, eB);
        LOADB(p3, bB0, bB1, bB2, bB3);          // reload B-buffer for chunk cc+3
        eA = eA2; eB = eB2;
    }
#undef PROC
#undef LOADB

    // reduce top-2 across the 16 col classes (lane bits 0..3)
#pragma unroll
    for (int mask = 1; mask < 16; mask <<= 1) {
#pragma unroll
        for (int s = 0; s < 2; ++s)
#pragma unroll
            for (int rg = 0; rg < 4; ++rg) {
                float ob = __shfl_xor(best[s][rg], mask);
                float os = __shfl_xor(sec[s][rg], mask);
                int   oi = __shfl_xor(bidx[s][rg], mask);
                if (ob > best[s][rg] || (ob == best[s][rg] && oi < bidx[s][rg])) {
                    sec[s][rg] = fmaxf(best[s][rg], os);
                    best[s][rg] = ob; bidx[s][rg] = oi;
                } else {
                    sec[s][rg] = fmaxf(sec[s][rg], ob);
                }
            }
    }
    if (n == 0) {
#pragma unroll
        for (int s = 0; s < 2; ++s)
#pragma unroll
            for (int rg = 0; rg < 4; ++rg) {
                int R = (int)row0 + w * 32 + s * 16 + q * 4 + rg;
                outi[R] = (float)bidx[s][rg];
                if (best[s][rg] - sec[s][rg] < TAU_ACC) {
                    int p = atomicAdd(fcnt_g, 1);
                    flags[p] = R;
                }
            }
    }
}

// ---------- dispatch 2: parallel exact fp32 refine, one BLOCK per flagged row ----------
// Per-code arithmetic identical to the passing cooperative refine (r4).
__global__ __launch_bounds__(256, 4)
void refine_kernel(const float* __restrict__ x, const float* __restrict__ embed,
                   const float* __restrict__ enorm, const int* __restrict__ fcnt_g,
                   const int* __restrict__ flags, float* __restrict__ outi) {
    __shared__ float rbest[4];
    __shared__ int   rbidx[4];
    const int tid  = threadIdx.x;
    const int w    = tid >> 6;
    const int lane = tid & 63;
    const int nf = *fcnt_g;
    for (int f = blockIdx.x; f < nf; f += gridDim.x) {
        int R = flags[f];
        const float4* xg4 = (const float4*)(x + (size_t)R * DIM);
        float b = -3.4e38f; int bi = 0;
        int cbase = tid * 4;
        for (int c = cbase; c < cbase + 4; ++c) {
            const float4* eg4 = (const float4*)(embed + (size_t)c * DIM);
            float s = 0.f;
#pragma unroll 8
            for (int d = 0; d < DIM / 4; ++d) {
                float4 xv = xg4[d], ev = eg4[d];
                s = fmaf(xv.x, ev.x, s); s = fmaf(xv.y, ev.y, s);
                s = fmaf(xv.z, ev.z, s); s = fmaf(xv.w, ev.w, s);
            }
            float sc = fmaf(2.f, s, -enorm[c]);
            if (sc > b) { b = sc; bi = c; }
        }
#pragma unroll
        for (int mask = 1; mask < 64; mask <<= 1) {
            float ob = __shfl_xor(b, mask);
            int   oi = __shfl_xor(bi, mask);
            if (ob > b || (ob == b && oi < bi)) { b = ob; bi = oi; }
        }
        if (lane == 0) { rbest[w] = b; rbidx[w] = bi; }
        __syncthreads();
        if (tid == 0) {
            float B = rbest[0]; int BI = rbidx[0];
#pragma unroll
            for (int i = 1; i < 4; ++i)
                if (rbest[i] > B || (rbest[i] == B && rbidx[i] < BI)) { B = rbest[i]; BI = rbidx[i]; }
            outi[R] = (float)BI;
        }
        __syncthreads();
    }
}

// ---------- dispatch 3: pure streaming gather (embed L2-resident) ----------
__global__ __launch_bounds__(256, 8)
void gather_kernel(const float* __restrict__ embed, const float* __restrict__ outi,
                   float* __restrict__ outq) {
    int g = blockIdx.x * 256 + threadIdx.x;      // over n_rows*32 float4s
    int r = g >> 5, d4 = g & 31;
    int id = (int)outi[r];
    ((float4*)outq)[g] = ((const float4*)embed)[(size_t)id * (DIM / 4) + d4];
}

extern "C" void kernel_launch(void* const* d_in, const int* in_sizes, int n_in,
                              void* d_out, int out_size, void* d_ws, size_t ws_size,
                              hipStream_t stream) {
    const float* x     = (const float*)d_in[0];
    const float* embed = (const float*)d_in[1];
    const int x_elems  = in_sizes[0];          // 12,288,000
    const int n_rows   = x_elems / DIM;        // 96,000

    float*    enorm = (float*)d_ws;                                   // [0, 4KB)
    int*      fcnt  = (int*)((char*)d_ws + 4096);                     // [4KB, +4)
    int*      flags = (int*)((char*)d_ws + 8192);                     // [8KB, 392KB) worst case
    _Float16* Ehp   = (_Float16*)((char*)d_ws + 8192 + n_rows * 4);   // 256 KB

    float* outq = (float*)d_out;
    float* outi = (float*)d_out + (size_t)x_elems;

    enorm_kernel<<<KCODES / 256, 256, 0, stream>>>(embed, enorm, fcnt);
    pack_kernel<<<KCODES * 16 / 256, 256, 0, stream>>>(embed, Ehp);
    argmax_mfma_kernel<<<n_rows / BROWS, 256, 0, stream>>>(x, Ehp, enorm, outi, fcnt, flags);
    refine_kernel<<<2048, 256, 0, stream>>>(x, embed, enorm, fcnt, flags, outi);
    gather_kernel<<<n_rows * (DIM / 4) / 256, 256, 0, stream>>>(embed, outi, outq);
}